// Round 4
// baseline (1166.869 us; speedup 1.0000x reference)
//
#include <hip/hip_runtime.h>

#define N_FEAT 512
#define HID 128
#define LAT 64

// CSR build constants
#define NB 98          // buckets: node >> BSHIFT
#define BSHIFT 10      // 1024 nodes per bucket
#define BS 1024        // bucket node span
#define CAP 34816      // per-bucket edge capacity (E/NB ~ 32653, 12 sigma margin)
#define CHUNK 4096     // edges per phase-1 block

// ---------------- degree histogram (global atomics, counts is L2-resident 400KB) ----------------
__global__ void hist_kernel(const int* __restrict__ dst, int* __restrict__ counts, int E) {
    int idx = blockIdx.x * blockDim.x + threadIdx.x;
    int stride = gridDim.x * blockDim.x;
    for (int e = idx; e < E; e += stride)
        atomicAdd(&counts[dst[e]], 1);
}

__global__ void dis_kernel(const int* __restrict__ counts, float* __restrict__ dis, int n) {
    int i = blockIdx.x * blockDim.x + threadIdx.x;
    if (i < n) dis[i] = rsqrtf((float)(counts[i] + 1));  // +1 self loop
}

// ---------------- phase 1: bin edges by dst bucket (LDS staged, contiguous flush) ----------------
__global__ __launch_bounds__(256) void bin_kernel(const int* __restrict__ src,
                                                  const int* __restrict__ dst,
                                                  int* __restrict__ gcursor,
                                                  uint2* __restrict__ binned, int E) {
    __shared__ int hist[NB];
    __shared__ int basel[NB];
    __shared__ int gbase[NB];
    __shared__ int cursor[NB];
    __shared__ uint2 staged[CHUNK];
    __shared__ unsigned short slotb[CHUNK];
    int tid = threadIdx.x;
    int e0 = blockIdx.x * CHUNK;
    int nE = min(CHUNK, E - e0);
    if (nE <= 0) return;
    for (int i = tid; i < NB; i += 256) hist[i] = 0;
    __syncthreads();
    for (int i = tid; i < nE; i += 256) {
        int d = dst[e0 + i];
        atomicAdd(&hist[d >> BSHIFT], 1);
    }
    __syncthreads();
    if (tid == 0) {
        int run = 0;
        for (int b = 0; b < NB; ++b) { basel[b] = run; run += hist[b]; }
    }
    __syncthreads();
    if (tid < NB) {
        int c = hist[tid];
        gbase[tid] = (c > 0) ? atomicAdd(&gcursor[tid], c) : 0;
        cursor[tid] = basel[tid];
    }
    __syncthreads();
    for (int i = tid; i < nE; i += 256) {
        int s = src[e0 + i];
        int d = dst[e0 + i];
        int b = d >> BSHIFT;
        int pos = atomicAdd(&cursor[b], 1);
        staged[pos] = make_uint2((unsigned)s, (unsigned)d);
        slotb[pos] = (unsigned short)b;
    }
    __syncthreads();
    for (int i = tid; i < nE; i += 256) {
        int b = slotb[i];
        int ofs = gbase[b] + (i - basel[b]);
        if (ofs < CAP) binned[(size_t)b * CAP + ofs] = staged[i];
    }
}

// ---------------- phase 2: per-bucket scatter into (src, dis[src]) pairs + offsets ----------------
__global__ __launch_bounds__(256) void build_kernel(const uint2* __restrict__ binned,
                                                    const int* __restrict__ gcursor,
                                                    const int* __restrict__ counts,
                                                    const float* __restrict__ dis,
                                                    int2* __restrict__ pairs,
                                                    int* __restrict__ offsets, int N) {
    __shared__ int nh[BS];
    __shared__ int excl[BS];
    __shared__ int ssum[256];
    int b = blockIdx.x;
    int tid = threadIdx.x;
    int nEdges = min(gcursor[b], CAP);
    int nodeBase = b << BSHIFT;
    const uint2* rgn = binned + (size_t)b * CAP;
    for (int i = tid; i < BS; i += 256) {
        int node = nodeBase + i;
        nh[i] = (node < N) ? counts[node] : 0;
    }
    __syncthreads();
    // exclusive scan of 1024 via per-thread 4-segments + Hillis-Steele over 256
    int t4 = tid * 4;
    int s0 = nh[t4], s1 = nh[t4 + 1], s2 = nh[t4 + 2], s3 = nh[t4 + 3];
    int segsum = s0 + s1 + s2 + s3;
    ssum[tid] = segsum; __syncthreads();
    for (int off = 1; off < 256; off <<= 1) {
        int x = (tid >= off) ? ssum[tid - off] : 0;
        __syncthreads();
        ssum[tid] += x;
        __syncthreads();
    }
    int segExcl = ssum[tid] - segsum;
    excl[t4] = segExcl;
    excl[t4 + 1] = segExcl + s0;
    excl[t4 + 2] = segExcl + s0 + s1;
    excl[t4 + 3] = segExcl + s0 + s1 + s2;
    __syncthreads();
    int csrBase = b * CAP;
    for (int i = tid; i < BS; i += 256) {
        int node = nodeBase + i;
        if (node < N) offsets[node] = csrBase + excl[i];
    }
    __syncthreads();
    for (int i = tid; i < BS; i += 256) nh[i] = excl[i];
    __syncthreads();
    // scatter (src, dis[src]) into this bucket's L2-resident pairs region
    for (int i = tid; i < nEdges; i += 256) {
        uint2 e = rgn[i];
        int pos = atomicAdd(&nh[e.y & (BS - 1)], 1);
        float ws = dis[e.x];   // 400KB, L2-hot
        pairs[csrBase + pos] = make_int2((int)e.x, __float_as_int(ws));
    }
}

// ---------------- GEMM1: t = X @ W1   (M x 512) @ (512 x 128), 128x128 tile ----------------
#define G1_BM 128
#define G1_BN 128
#define G1_BK 16
__global__ __launch_bounds__(256) void gemm1_kernel(const float* __restrict__ X,
                                                    const float* __restrict__ W,
                                                    float* __restrict__ T, int M) {
    __shared__ float As[G1_BK][G1_BM];   // K-major: a-frag reads are contiguous b128
    __shared__ float Bs[G1_BK][G1_BN];
    int tid = threadIdx.x;
    int bm = blockIdx.x * G1_BM;
    int tx = tid & 15;        // col0 = tx*8
    int ty = tid >> 4;        // row0 = ty*8

    int a_row = tid >> 1;               // 0..127
    int a_kq = (tid & 1) << 3;          // 0 or 8
    int a_row_g = bm + a_row;
    int a_row_c = a_row_g < M ? a_row_g : (M - 1);
    int b_row = tid >> 4;               // 0..15
    int b_col = (tid & 15) << 3;        // 0..120

    float acc[8][8];
    #pragma unroll
    for (int i = 0; i < 8; ++i)
        #pragma unroll
        for (int j = 0; j < 8; ++j) acc[i][j] = 0.f;

    for (int k0 = 0; k0 < N_FEAT; k0 += G1_BK) {
        float4 av0 = *(const float4*)&X[(size_t)a_row_c * N_FEAT + k0 + a_kq];
        float4 av1 = *(const float4*)&X[(size_t)a_row_c * N_FEAT + k0 + a_kq + 4];
        float4 bv0 = *(const float4*)&W[(size_t)(k0 + b_row) * G1_BN + b_col];
        float4 bv1 = *(const float4*)&W[(size_t)(k0 + b_row) * G1_BN + b_col + 4];
        As[a_kq + 0][a_row] = av0.x; As[a_kq + 1][a_row] = av0.y;
        As[a_kq + 2][a_row] = av0.z; As[a_kq + 3][a_row] = av0.w;
        As[a_kq + 4][a_row] = av1.x; As[a_kq + 5][a_row] = av1.y;
        As[a_kq + 6][a_row] = av1.z; As[a_kq + 7][a_row] = av1.w;
        *(float4*)&Bs[b_row][b_col] = bv0;
        *(float4*)&Bs[b_row][b_col + 4] = bv1;
        __syncthreads();
        #pragma unroll
        for (int k = 0; k < G1_BK; ++k) {
            float4 a0 = *(const float4*)&As[k][ty * 8];
            float4 a1 = *(const float4*)&As[k][ty * 8 + 4];
            float4 b0 = *(const float4*)&Bs[k][tx * 8];
            float4 b1 = *(const float4*)&Bs[k][tx * 8 + 4];
            float aa[8] = {a0.x, a0.y, a0.z, a0.w, a1.x, a1.y, a1.z, a1.w};
            float bb[8] = {b0.x, b0.y, b0.z, b0.w, b1.x, b1.y, b1.z, b1.w};
            #pragma unroll
            for (int i = 0; i < 8; ++i)
                #pragma unroll
                for (int j = 0; j < 8; ++j) acc[i][j] += aa[i] * bb[j];
        }
        __syncthreads();
    }
    #pragma unroll
    for (int i = 0; i < 8; ++i) {
        int row = bm + ty * 8 + i;
        if (row < M) {
            float4 o0 = {acc[i][0], acc[i][1], acc[i][2], acc[i][3]};
            float4 o1 = {acc[i][4], acc[i][5], acc[i][6], acc[i][7]};
            *(float4*)&T[(size_t)row * HID + tx * 8] = o0;
            *(float4*)&T[(size_t)row * HID + tx * 8 + 4] = o1;
        }
    }
}

// ---------------- pull aggregation: half-wave per node, 8-deep software pipeline ----------------
template <bool RELU_BIAS>
__global__ __launch_bounds__(256) void agg_kernel(const float* __restrict__ T,
                                                  const int2* __restrict__ pairs,
                                                  const int* __restrict__ offsets,
                                                  const int* __restrict__ counts,
                                                  const float* __restrict__ dis,
                                                  const float* __restrict__ bias,
                                                  float* __restrict__ out, int n) {
    int tid = threadIdx.x;
    int half = tid >> 5;
    int lane = tid & 31;
    int i = blockIdx.x * 8 + half;
    if (i >= n) return;
    float di = dis[i];
    int beg = offsets[i];
    int cnt = counts[i];
    const int2* ep = pairs + beg;
    float4 self = ((const float4*)(T + (size_t)i * HID))[lane];
    float4 acc;
    acc.x = di * self.x; acc.y = di * self.y; acc.z = di * self.z; acc.w = di * self.w;
    if (cnt > 0) {
        int cm1 = cnt - 1;
        int s[8]; float w[8];
        #pragma unroll
        for (int u = 0; u < 8; ++u) {
            int2 p = ep[min(u, cm1)];
            s[u] = p.x;
            w[u] = (u <= cm1) ? __int_as_float(p.y) : 0.f;
        }
        for (int j = 0; j < cnt; j += 8) {
            float4 v[8];
            #pragma unroll
            for (int u = 0; u < 8; ++u)
                v[u] = ((const float4*)(T + (size_t)s[u] * HID))[lane];
            int jn = j + 8;
            int sN[8]; float wN[8];
            #pragma unroll
            for (int u = 0; u < 8; ++u) {
                int2 p = ep[min(jn + u, cm1)];
                sN[u] = p.x;
                wN[u] = (jn + u <= cm1) ? __int_as_float(p.y) : 0.f;
            }
            #pragma unroll
            for (int u = 0; u < 8; ++u) {
                acc.x += w[u] * v[u].x; acc.y += w[u] * v[u].y;
                acc.z += w[u] * v[u].z; acc.w += w[u] * v[u].w;
            }
            #pragma unroll
            for (int u = 0; u < 8; ++u) { s[u] = sN[u]; w[u] = wN[u]; }
        }
    }
    acc.x *= di; acc.y *= di; acc.z *= di; acc.w *= di;
    if (RELU_BIAS) {
        float4 bv = ((const float4*)bias)[lane];
        acc.x = fmaxf(acc.x + bv.x, 0.f);
        acc.y = fmaxf(acc.y + bv.y, 0.f);
        acc.z = fmaxf(acc.z + bv.z, 0.f);
        acc.w = fmaxf(acc.w + bv.w, 0.f);
    }
    ((float4*)(out + (size_t)i * HID))[lane] = acc;
}

// ---------------- GEMM2: [mean|var] = G @ [Wm|Wv] + [bm|bv], tiled ----------------
#define BM 64
#define BN 128
#define BK 16
__global__ __launch_bounds__(256) void gemm2_kernel(const float* __restrict__ G,
                                                    const float* __restrict__ Wm,
                                                    const float* __restrict__ bm,
                                                    const float* __restrict__ Wv,
                                                    const float* __restrict__ bv,
                                                    float* __restrict__ outm,
                                                    float* __restrict__ outv, int M) {
    __shared__ float As[BM][BK + 1];
    __shared__ float Bs[BK][BN];
    int tid = threadIdx.x;
    int block_m = blockIdx.x * BM;
    int tx = tid & 15;
    int ty = tid >> 4;

    int a_row = tid >> 2;
    int a_k4 = (tid & 3) << 2;
    int a_row_g = block_m + a_row;
    int a_row_c = a_row_g < M ? a_row_g : (M - 1);
    int b_row = tid >> 5;
    int b_col = (tid & 31) << 2;
    const float* Wsel = (b_col < 64) ? (Wm + b_col) : (Wv + (b_col - 64));

    float acc[4][8];
    #pragma unroll
    for (int i = 0; i < 4; ++i)
        #pragma unroll
        for (int j = 0; j < 8; ++j) acc[i][j] = 0.f;

    for (int k0 = 0; k0 < HID; k0 += BK) {
        float4 av = *(const float4*)&G[(size_t)a_row_c * HID + k0 + a_k4];
        float4 bv0 = *(const float4*)&Wsel[(size_t)(k0 + b_row) * LAT];
        float4 bv1 = *(const float4*)&Wsel[(size_t)(k0 + b_row + 8) * LAT];
        As[a_row][a_k4 + 0] = av.x; As[a_row][a_k4 + 1] = av.y;
        As[a_row][a_k4 + 2] = av.z; As[a_row][a_k4 + 3] = av.w;
        *(float4*)&Bs[b_row][b_col] = bv0;
        *(float4*)&Bs[b_row + 8][b_col] = bv1;
        __syncthreads();
        #pragma unroll
        for (int k = 0; k < BK; ++k) {
            float a[4];
            #pragma unroll
            for (int i = 0; i < 4; ++i) a[i] = As[ty * 4 + i][k];
            float4 bq0 = *(const float4*)&Bs[k][tx * 8];
            float4 bq1 = *(const float4*)&Bs[k][tx * 8 + 4];
            float bb[8] = {bq0.x, bq0.y, bq0.z, bq0.w, bq1.x, bq1.y, bq1.z, bq1.w};
            #pragma unroll
            for (int i = 0; i < 4; ++i)
                #pragma unroll
                for (int j = 0; j < 8; ++j) acc[i][j] += a[i] * bb[j];
        }
        __syncthreads();
    }

    int col0 = tx * 8;
    float* outsel = (col0 < 64) ? (outm + col0) : (outv + (col0 - 64));
    const float* bsel = (col0 < 64) ? (bm + col0) : (bv + (col0 - 64));
    float4 bb0 = *(const float4*)&bsel[0];
    float4 bb1 = *(const float4*)&bsel[4];
    #pragma unroll
    for (int i = 0; i < 4; ++i) {
        int row = block_m + ty * 4 + i;
        if (row < M) {
            float4 o0 = {acc[i][0] + bb0.x, acc[i][1] + bb0.y, acc[i][2] + bb0.z, acc[i][3] + bb0.w};
            float4 o1 = {acc[i][4] + bb1.x, acc[i][5] + bb1.y, acc[i][6] + bb1.z, acc[i][7] + bb1.w};
            *(float4*)&outsel[(size_t)row * LAT] = o0;
            *(float4*)&outsel[(size_t)row * LAT + 4] = o1;
        }
    }
}

extern "C" void kernel_launch(void* const* d_in, const int* in_sizes, int n_in,
                              void* d_out, int out_size, void* d_ws, size_t ws_size,
                              hipStream_t stream) {
    const float* X  = (const float*)d_in[0];
    const int* edge = (const int*)d_in[1];
    const float* W1 = (const float*)d_in[2];
    const float* b1 = (const float*)d_in[3];
    const float* Wm = (const float*)d_in[4];
    const float* bm = (const float*)d_in[5];
    const float* Wv = (const float*)d_in[6];
    const float* bv = (const float*)d_in[7];

    int N = in_sizes[0] / N_FEAT;     // 100000
    int E = in_sizes[1] / 2;          // 3200000
    const int* srcp = edge;
    const int* dstp = edge + E;

    char* w = (char*)d_ws;
    size_t off = 0;
    auto alloc = [&](size_t bytes) -> void* {
        void* p = w + off;
        off = (off + bytes + 511) & ~(size_t)511;
        return p;
    };
    float* dis    = (float*)alloc((size_t)N * 4);
    int* counts   = (int*)alloc((size_t)N * 4);
    int* offsets  = (int*)alloc((size_t)N * 4);
    int* gcursor  = (int*)alloc((size_t)NB * 4);
    int2* pairs   = (int2*)alloc((size_t)NB * CAP * 8);
    float* t      = (float*)alloc((size_t)N * HID * 4);
    float* h      = (float*)alloc((size_t)N * HID * 4);
    uint2* binned = (uint2*)h;   // alias: binned (27.3MB) dead before agg1 writes h
    float* g      = t;           // t dead after agg1; reuse for g

    hipMemsetAsync(counts, 0, (size_t)N * 4, stream);
    hipMemsetAsync(gcursor, 0, (size_t)NB * 4, stream);
    hist_kernel<<<2048, 256, 0, stream>>>(dstp, counts, E);
    dis_kernel<<<(N + 255) / 256, 256, 0, stream>>>(counts, dis, N);
    int nChunks = (E + CHUNK - 1) / CHUNK;
    bin_kernel<<<nChunks, 256, 0, stream>>>(srcp, dstp, gcursor, binned, E);
    build_kernel<<<NB, 256, 0, stream>>>(binned, gcursor, counts, dis, pairs, offsets, N);

    gemm1_kernel<<<(N + G1_BM - 1) / G1_BM, 256, 0, stream>>>(X, W1, t, N);
    agg_kernel<true><<<(N + 7) / 8, 256, 0, stream>>>(t, pairs, offsets, counts, dis, b1, h, N);
    agg_kernel<false><<<(N + 7) / 8, 256, 0, stream>>>(h, pairs, offsets, counts, dis, nullptr, g, N);

    float* outm = (float*)d_out;
    float* outv = outm + (size_t)N * LAT;
    gemm2_kernel<<<(N + BM - 1) / BM, 256, 0, stream>>>(g, Wm, bm, Wv, bv, outm, outv, N);
}

// Round 5
// 981.542 us; speedup vs baseline: 1.1888x; 1.1888x over previous
//
#include <hip/hip_runtime.h>

#define N_FEAT 512
#define HID 128
#define LAT 64

// CSR build constants
#define NB 98          // buckets: node >> BSHIFT
#define BSHIFT 10      // 1024 nodes per bucket
#define BS 1024        // bucket node span
#define CAP 34816      // per-bucket edge capacity (E/NB ~ 32653, 12 sigma margin)
#define CHUNK 4096     // edges per phase-1 block

__device__ __forceinline__ unsigned short f2bf(float f) {
    unsigned u = __float_as_uint(f);
    return (unsigned short)((u + 0x7FFFu + ((u >> 16) & 1u)) >> 16);   // RNE
}
__device__ __forceinline__ float bf2f(unsigned short h) {
    return __uint_as_float(((unsigned)h) << 16);
}

// ---------------- phase 1: bin edges by dst bucket + per-node degree histogram ----------------
__global__ __launch_bounds__(256) void bin_kernel(const int* __restrict__ src,
                                                  const int* __restrict__ dst,
                                                  int* __restrict__ gcursor,
                                                  int* __restrict__ counts,
                                                  uint2* __restrict__ binned, int E) {
    __shared__ int hist[NB];
    __shared__ int basel[NB];
    __shared__ int gbase[NB];
    __shared__ int cursor[NB];
    __shared__ uint2 staged[CHUNK];
    __shared__ unsigned short slotb[CHUNK];
    int tid = threadIdx.x;
    int e0 = blockIdx.x * CHUNK;
    int nE = min(CHUNK, E - e0);
    if (nE <= 0) return;
    for (int i = tid; i < NB; i += 256) hist[i] = 0;
    __syncthreads();
    for (int i = tid; i < nE; i += 256) {
        int d = dst[e0 + i];
        atomicAdd(&hist[d >> BSHIFT], 1);
        atomicAdd(&counts[d], 1);          // per-node degree (L2-resident 400KB)
    }
    __syncthreads();
    if (tid == 0) {
        int run = 0;
        for (int b = 0; b < NB; ++b) { basel[b] = run; run += hist[b]; }
    }
    __syncthreads();
    if (tid < NB) {
        int c = hist[tid];
        gbase[tid] = (c > 0) ? atomicAdd(&gcursor[tid], c) : 0;
        cursor[tid] = basel[tid];
    }
    __syncthreads();
    for (int i = tid; i < nE; i += 256) {
        int s = src[e0 + i];
        int d = dst[e0 + i];
        int b = d >> BSHIFT;
        int pos = atomicAdd(&cursor[b], 1);
        staged[pos] = make_uint2((unsigned)s, (unsigned)d);
        slotb[pos] = (unsigned short)b;
    }
    __syncthreads();
    for (int i = tid; i < nE; i += 256) {
        int b = slotb[i];
        int ofs = gbase[b] + (i - basel[b]);
        if (ofs < CAP) binned[(size_t)b * CAP + ofs] = staged[i];
    }
}

__global__ void dis_kernel(const int* __restrict__ counts, float* __restrict__ dis, int n) {
    int i = blockIdx.x * blockDim.x + threadIdx.x;
    if (i < n) dis[i] = rsqrtf((float)(counts[i] + 1));  // +1 self loop
}

// ---------------- phase 2: per-bucket scatter into (src, dis[src]) pairs + offsets ----------------
__global__ __launch_bounds__(256) void build_kernel(const uint2* __restrict__ binned,
                                                    const int* __restrict__ gcursor,
                                                    const int* __restrict__ counts,
                                                    const float* __restrict__ dis,
                                                    int2* __restrict__ pairs,
                                                    int* __restrict__ offsets, int N) {
    __shared__ int nh[BS];
    __shared__ int excl[BS];
    __shared__ int ssum[256];
    int b = blockIdx.x;
    int tid = threadIdx.x;
    int nEdges = min(gcursor[b], CAP);
    int nodeBase = b << BSHIFT;
    const uint2* rgn = binned + (size_t)b * CAP;
    for (int i = tid; i < BS; i += 256) {
        int node = nodeBase + i;
        nh[i] = (node < N) ? counts[node] : 0;
    }
    __syncthreads();
    int t4 = tid * 4;
    int s0 = nh[t4], s1 = nh[t4 + 1], s2 = nh[t4 + 2], s3 = nh[t4 + 3];
    int segsum = s0 + s1 + s2 + s3;
    ssum[tid] = segsum; __syncthreads();
    for (int off = 1; off < 256; off <<= 1) {
        int x = (tid >= off) ? ssum[tid - off] : 0;
        __syncthreads();
        ssum[tid] += x;
        __syncthreads();
    }
    int segExcl = ssum[tid] - segsum;
    excl[t4] = segExcl;
    excl[t4 + 1] = segExcl + s0;
    excl[t4 + 2] = segExcl + s0 + s1;
    excl[t4 + 3] = segExcl + s0 + s1 + s2;
    __syncthreads();
    int csrBase = b * CAP;
    for (int i = tid; i < BS; i += 256) {
        int node = nodeBase + i;
        if (node < N) offsets[node] = csrBase + excl[i];
    }
    __syncthreads();
    for (int i = tid; i < BS; i += 256) nh[i] = excl[i];
    __syncthreads();
    for (int i = tid; i < nEdges; i += 256) {
        uint2 e = rgn[i];
        int pos = atomicAdd(&nh[e.y & (BS - 1)], 1);
        float ws = dis[e.x];   // 400KB, L2-hot
        pairs[csrBase + pos] = make_int2((int)e.x, __float_as_int(ws));
    }
}

// ---------------- GEMM1: t = X @ W1 (bf16 out), 64x128 tile (R3-proven) ----------------
#define BM 64
#define BN 128
#define BK 16
__global__ __launch_bounds__(256) void gemm1_kernel(const float* __restrict__ X,
                                                    const float* __restrict__ W,
                                                    unsigned short* __restrict__ Tb, int M) {
    __shared__ float As[BM][BK + 1];
    __shared__ float Bs[BK][BN];
    int tid = threadIdx.x;
    int block_m = blockIdx.x * BM;
    int tx = tid & 15;
    int ty = tid >> 4;

    int a_row = tid >> 2;
    int a_k4 = (tid & 3) << 2;
    int a_row_g = block_m + a_row;
    int a_row_c = a_row_g < M ? a_row_g : (M - 1);
    int b_row = tid >> 5;
    int b_col = (tid & 31) << 2;

    float acc[4][8];
    #pragma unroll
    for (int i = 0; i < 4; ++i)
        #pragma unroll
        for (int j = 0; j < 8; ++j) acc[i][j] = 0.f;

    for (int k0 = 0; k0 < N_FEAT; k0 += BK) {
        float4 av = *(const float4*)&X[(size_t)a_row_c * N_FEAT + k0 + a_k4];
        float4 bv0 = *(const float4*)&W[(size_t)(k0 + b_row) * BN + b_col];
        float4 bv1 = *(const float4*)&W[(size_t)(k0 + b_row + 8) * BN + b_col];
        As[a_row][a_k4 + 0] = av.x; As[a_row][a_k4 + 1] = av.y;
        As[a_row][a_k4 + 2] = av.z; As[a_row][a_k4 + 3] = av.w;
        *(float4*)&Bs[b_row][b_col] = bv0;
        *(float4*)&Bs[b_row + 8][b_col] = bv1;
        __syncthreads();
        #pragma unroll
        for (int k = 0; k < BK; ++k) {
            float a[4];
            #pragma unroll
            for (int i = 0; i < 4; ++i) a[i] = As[ty * 4 + i][k];
            float4 bq0 = *(const float4*)&Bs[k][tx * 8];
            float4 bq1 = *(const float4*)&Bs[k][tx * 8 + 4];
            float bb[8] = {bq0.x, bq0.y, bq0.z, bq0.w, bq1.x, bq1.y, bq1.z, bq1.w};
            #pragma unroll
            for (int i = 0; i < 4; ++i)
                #pragma unroll
                for (int j = 0; j < 8; ++j) acc[i][j] += a[i] * bb[j];
        }
        __syncthreads();
    }
    #pragma unroll
    for (int i = 0; i < 4; ++i) {
        int row = block_m + ty * 4 + i;
        if (row < M) {
            ushort4 o0 = {f2bf(acc[i][0]), f2bf(acc[i][1]), f2bf(acc[i][2]), f2bf(acc[i][3])};
            ushort4 o1 = {f2bf(acc[i][4]), f2bf(acc[i][5]), f2bf(acc[i][6]), f2bf(acc[i][7])};
            *(ushort4*)&Tb[(size_t)row * HID + tx * 8] = o0;
            *(ushort4*)&Tb[(size_t)row * HID + tx * 8 + 4] = o1;
        }
    }
}

// ---------------- pull aggregation over bf16 rows: half-wave per node, 8-deep pipeline ----------------
template <bool RELU_BIAS, bool OUT_BF16>
__global__ __launch_bounds__(256) void agg_kernel(const unsigned short* __restrict__ Tb,
                                                  const int2* __restrict__ pairs,
                                                  const int* __restrict__ offsets,
                                                  const int* __restrict__ counts,
                                                  const float* __restrict__ dis,
                                                  const float* __restrict__ bias,
                                                  void* __restrict__ out, int n) {
    int tid = threadIdx.x;
    int half = tid >> 5;
    int lane = tid & 31;
    int i = blockIdx.x * 8 + half;
    if (i >= n) return;
    float di = dis[i];
    int beg = offsets[i];
    int cnt = counts[i];
    const int2* ep = pairs + beg;
    ushort4 self = ((const ushort4*)(Tb + (size_t)i * HID))[lane];
    float4 acc;
    acc.x = di * bf2f(self.x); acc.y = di * bf2f(self.y);
    acc.z = di * bf2f(self.z); acc.w = di * bf2f(self.w);
    if (cnt > 0) {
        int cm1 = cnt - 1;
        int s[8]; float w[8];
        #pragma unroll
        for (int u = 0; u < 8; ++u) {
            int2 p = ep[min(u, cm1)];
            s[u] = p.x;
            w[u] = (u <= cm1) ? __int_as_float(p.y) : 0.f;
        }
        for (int j = 0; j < cnt; j += 8) {
            ushort4 v[8];
            #pragma unroll
            for (int u = 0; u < 8; ++u)
                v[u] = ((const ushort4*)(Tb + (size_t)s[u] * HID))[lane];
            int jn = j + 8;
            int sN[8]; float wN[8];
            #pragma unroll
            for (int u = 0; u < 8; ++u) {
                int2 p = ep[min(jn + u, cm1)];
                sN[u] = p.x;
                wN[u] = (jn + u <= cm1) ? __int_as_float(p.y) : 0.f;
            }
            #pragma unroll
            for (int u = 0; u < 8; ++u) {
                acc.x += w[u] * bf2f(v[u].x); acc.y += w[u] * bf2f(v[u].y);
                acc.z += w[u] * bf2f(v[u].z); acc.w += w[u] * bf2f(v[u].w);
            }
            #pragma unroll
            for (int u = 0; u < 8; ++u) { s[u] = sN[u]; w[u] = wN[u]; }
        }
    }
    acc.x *= di; acc.y *= di; acc.z *= di; acc.w *= di;
    if (RELU_BIAS) {
        float4 bv = ((const float4*)bias)[lane];
        acc.x = fmaxf(acc.x + bv.x, 0.f);
        acc.y = fmaxf(acc.y + bv.y, 0.f);
        acc.z = fmaxf(acc.z + bv.z, 0.f);
        acc.w = fmaxf(acc.w + bv.w, 0.f);
    }
    if (OUT_BF16) {
        ushort4 o = {f2bf(acc.x), f2bf(acc.y), f2bf(acc.z), f2bf(acc.w)};
        ((ushort4*)((unsigned short*)out + (size_t)i * HID))[lane] = o;
    } else {
        ((float4*)((float*)out + (size_t)i * HID))[lane] = acc;
    }
}

// ---------------- GEMM2: [mean|var] = G @ [Wm|Wv] + [bm|bv], tiled ----------------
__global__ __launch_bounds__(256) void gemm2_kernel(const float* __restrict__ G,
                                                    const float* __restrict__ Wm,
                                                    const float* __restrict__ bm,
                                                    const float* __restrict__ Wv,
                                                    const float* __restrict__ bv,
                                                    float* __restrict__ outm,
                                                    float* __restrict__ outv, int M) {
    __shared__ float As[BM][BK + 1];
    __shared__ float Bs[BK][BN];
    int tid = threadIdx.x;
    int block_m = blockIdx.x * BM;
    int tx = tid & 15;
    int ty = tid >> 4;

    int a_row = tid >> 2;
    int a_k4 = (tid & 3) << 2;
    int a_row_g = block_m + a_row;
    int a_row_c = a_row_g < M ? a_row_g : (M - 1);
    int b_row = tid >> 5;
    int b_col = (tid & 31) << 2;
    const float* Wsel = (b_col < 64) ? (Wm + b_col) : (Wv + (b_col - 64));

    float acc[4][8];
    #pragma unroll
    for (int i = 0; i < 4; ++i)
        #pragma unroll
        for (int j = 0; j < 8; ++j) acc[i][j] = 0.f;

    for (int k0 = 0; k0 < HID; k0 += BK) {
        float4 av = *(const float4*)&G[(size_t)a_row_c * HID + k0 + a_k4];
        float4 bv0 = *(const float4*)&Wsel[(size_t)(k0 + b_row) * LAT];
        float4 bv1 = *(const float4*)&Wsel[(size_t)(k0 + b_row + 8) * LAT];
        As[a_row][a_k4 + 0] = av.x; As[a_row][a_k4 + 1] = av.y;
        As[a_row][a_k4 + 2] = av.z; As[a_row][a_k4 + 3] = av.w;
        *(float4*)&Bs[b_row][b_col] = bv0;
        *(float4*)&Bs[b_row + 8][b_col] = bv1;
        __syncthreads();
        #pragma unroll
        for (int k = 0; k < BK; ++k) {
            float a[4];
            #pragma unroll
            for (int i = 0; i < 4; ++i) a[i] = As[ty * 4 + i][k];
            float4 bq0 = *(const float4*)&Bs[k][tx * 8];
            float4 bq1 = *(const float4*)&Bs[k][tx * 8 + 4];
            float bb[8] = {bq0.x, bq0.y, bq0.z, bq0.w, bq1.x, bq1.y, bq1.z, bq1.w};
            #pragma unroll
            for (int i = 0; i < 4; ++i)
                #pragma unroll
                for (int j = 0; j < 8; ++j) acc[i][j] += a[i] * bb[j];
        }
        __syncthreads();
    }

    int col0 = tx * 8;
    float* outsel = (col0 < 64) ? (outm + col0) : (outv + (col0 - 64));
    const float* bsel = (col0 < 64) ? (bm + col0) : (bv + (col0 - 64));
    float4 bb0 = *(const float4*)&bsel[0];
    float4 bb1 = *(const float4*)&bsel[4];
    #pragma unroll
    for (int i = 0; i < 4; ++i) {
        int row = block_m + ty * 4 + i;
        if (row < M) {
            float4 o0 = {acc[i][0] + bb0.x, acc[i][1] + bb0.y, acc[i][2] + bb0.z, acc[i][3] + bb0.w};
            float4 o1 = {acc[i][4] + bb1.x, acc[i][5] + bb1.y, acc[i][6] + bb1.z, acc[i][7] + bb1.w};
            *(float4*)&outsel[(size_t)row * LAT] = o0;
            *(float4*)&outsel[(size_t)row * LAT + 4] = o1;
        }
    }
}

extern "C" void kernel_launch(void* const* d_in, const int* in_sizes, int n_in,
                              void* d_out, int out_size, void* d_ws, size_t ws_size,
                              hipStream_t stream) {
    const float* X  = (const float*)d_in[0];
    const int* edge = (const int*)d_in[1];
    const float* W1 = (const float*)d_in[2];
    const float* b1 = (const float*)d_in[3];
    const float* Wm = (const float*)d_in[4];
    const float* bm = (const float*)d_in[5];
    const float* Wv = (const float*)d_in[6];
    const float* bv = (const float*)d_in[7];

    int N = in_sizes[0] / N_FEAT;     // 100000
    int E = in_sizes[1] / 2;          // 3200000
    const int* srcp = edge;
    const int* dstp = edge + E;

    char* w = (char*)d_ws;
    size_t off = 0;
    auto alloc = [&](size_t bytes) -> void* {
        void* p = w + off;
        off = (off + bytes + 511) & ~(size_t)511;
        return p;
    };
    float* dis    = (float*)alloc((size_t)N * 4);
    int* counts   = (int*)alloc((size_t)N * 4);
    int* offsets  = (int*)alloc((size_t)N * 4);
    int* gcursor  = (int*)alloc((size_t)NB * 4);
    int2* pairs   = (int2*)alloc((size_t)NB * CAP * 8);
    unsigned short* tb = (unsigned short*)alloc((size_t)N * HID * 2);  // bf16 t
    unsigned short* hb = (unsigned short*)alloc((size_t)N * HID * 2);  // bf16 h
    float* g      = (float*)alloc((size_t)N * HID * 4);                // fp32 g
    uint2* binned = (uint2*)g;   // alias: binned (27.3MB) dead before agg2 writes g (51.2MB)

    hipMemsetAsync(counts, 0, (size_t)N * 4, stream);
    hipMemsetAsync(gcursor, 0, (size_t)NB * 4, stream);
    int nChunks = (E + CHUNK - 1) / CHUNK;
    bin_kernel<<<nChunks, 256, 0, stream>>>(srcp, dstp, gcursor, counts, binned, E);
    dis_kernel<<<(N + 255) / 256, 256, 0, stream>>>(counts, dis, N);
    build_kernel<<<NB, 256, 0, stream>>>(binned, gcursor, counts, dis, pairs, offsets, N);

    gemm1_kernel<<<(N + BM - 1) / BM, 256, 0, stream>>>(X, W1, tb, N);
    agg_kernel<true, true><<<(N + 7) / 8, 256, 0, stream>>>(tb, pairs, offsets, counts, dis, b1, hb, N);
    agg_kernel<false, false><<<(N + 7) / 8, 256, 0, stream>>>(hb, pairs, offsets, counts, dis, nullptr, g, N);

    float* outm = (float*)d_out;
    float* outv = outm + (size_t)N * LAT;
    gemm2_kernel<<<(N + BM - 1) / BM, 256, 0, stream>>>(g, Wm, bm, Wv, bv, outm, outv, N);
}